// Round 6
// baseline (352.362 us; speedup 1.0000x reference)
//
#include <hip/hip_runtime.h>
#include <stdint.h>

#define N_ROWS 32768
#define K_CODES 8192
#define D_DIM 256
#define STEP_BYTES 33024   // 32 KiB bf16 codes + 256 B fp32 c2 table (16B-aligned)
#define NBUF 4

typedef __attribute__((ext_vector_type(8))) short short8;
typedef __attribute__((ext_vector_type(4))) float f32x4;

__device__ __forceinline__ unsigned short f2bf_rne(float f) {
  union { float f; unsigned u; } v; v.f = f;
  unsigned r = v.u + 0x7fffu + ((v.u >> 16) & 1u);
  return (unsigned short)(r >> 16);
}

// ---------------------------------------------------------------------------
// Prep: codebook fp32 -> bf16 (RNE), XOR-swizzled within each 512B row.
// Each 64-code step tile carries a 256 B fp32 |e|^2 table (exact c2).
// Zeroes counts.
// ---------------------------------------------------------------------------
__global__ __launch_bounds__(256) void eprep_kernel(
    const float* __restrict__ cb, unsigned short* __restrict__ ehw,
    int* __restrict__ counts) {
  int w = threadIdx.x >> 6, lane = threadIdx.x & 63;
  int k = blockIdx.x * 4 + w;
  int gid = blockIdx.x * 256 + threadIdx.x;
  if (gid < K_CODES) counts[gid] = 0;
  const float4* src = (const float4*)(cb + (size_t)k * D_DIM);
  float4 v = src[lane];
  float vv[4] = {v.x, v.y, v.z, v.w};
  unsigned short h[4];
  float s = 0.f;
#pragma unroll
  for (int j = 0; j < 4; ++j) {
    float f = vv[j];
    s += f * f;
    h[j] = f2bf_rne(f);
  }
  char* stepb = (char*)ehw + (size_t)(k >> 6) * STEP_BYTES;
  int cl = k & 63;
  int off = (8 * lane) ^ ((k & 7) << 4);  // swizzle flips bits 4-6 only
  *(ushort4*)(stepb + cl * 512 + off) = make_ushort4(h[0], h[1], h[2], h[3]);
#pragma unroll
  for (int m = 1; m < 64; m <<= 1) s += __shfl_xor(s, m);
  if (lane == 0) *(float*)(stepb + 32768 + cl * 4) = s;  // fp32-exact |e|^2
}

// ---------------------------------------------------------------------------
// Argmin, R6: CU-space role split. HBM doesn't care which CU issues the
// writes, so stop making every wave carry stage-wait + barrier + store-ack
// in lockstep (R5 showed that structure is ~35% over the drain floor and
// can't be decoupled further within the in-order vmcnt counter).
//   blocks   0..127: COMPUTE — the proven T3+T4 loads-only pipeline
//            (5 loads/iter, waits 10/10/5/0), run TWICE (256 rows/block,
//            pass p handles rows b*256 + p*128). No global stores in loop.
//   blocks 128..255: STORER — pure zero-fill of an 8 MiB enc chunk with
//            aligned global_store_dwordx4 nt (full 128B lines; nt keeps the
//            1.07 GB stream from evicting ehw out of L2 — R3 lesson),
//            free-running, no barriers, paced only by HBM drain.
// The one-hot 1.0 scatter moves to scatter_kernel (must order after foreign
// blocks' zeros => kernel boundary). All blocks: 512 thr + 129 KiB LDS so
// grid=256 maps exactly 1 block/CU (128 compute + 128 storer co-resident).
// ---------------------------------------------------------------------------
__global__ __launch_bounds__(512, 1) void argmin_kernel(
    const float* __restrict__ x, const float* __restrict__ cb,
    const unsigned short* __restrict__ ehw,
    float* __restrict__ quant, int* __restrict__ counts,
    float* __restrict__ ssep, int* __restrict__ idxb,
    float* __restrict__ enc) {
  __shared__ __align__(16) char s_tiles[NBUF * STEP_BYTES];  // 129 KiB
  __shared__ float s_x2[128];
  __shared__ float s_red[128];
  // epilogue-only arrays aliased onto s_tiles (tiles dead after the K loop;
  // end-of-pass __syncthreads orders reuse before the next pass re-stages):
  float (*s_mn)[128] = (float (*)[128])(s_tiles);          // 2 KiB
  int (*s_mi)[128] = (int (*)[128])(s_tiles + 2048);       // 2 KiB

  const int tid = threadIdx.x;
  const int abid = blockIdx.x;
  const int ww = tid >> 6;
  const int lane = tid & 63;
  const f32x4 z4 = {0.f, 0.f, 0.f, 0.f};

  // ---------------- STORER ROLE ----------------
  if (abid >= 128) {
    const int b2 = abid - 128;
    char* base = (char*)enc + (size_t)b2 * 8388608;   // chunk, base == 8 mod 128
    // head 120 B + tail 8 B of this chunk (scalar stores)
    if (tid < 30) ((float*)base)[tid] = 0.f;
    if (tid < 2) *(float*)(base + 8388600 + 4 * tid) = 0.f;
    // aligned bulk: 65535 lines at base+120. waves 0-6: 8192 lines (1024
    // 1KiB-instrs); wave 7: 8191 lines (1023 instrs + 7-line predicated).
    char* wp = base + 120 + (size_t)ww * 1048576 + lane * 16;
    const int nst = (ww < 7) ? 1024 : 1023;
#pragma unroll 1
    for (int i = 0; i < nst; i += 8) {
#pragma unroll
      for (int j = 0; j < 8; ++j) {
        if (i + j < nst) {
          asm volatile("global_store_dwordx4 %0, %1, off nt"
                       :: "v"(wp + (size_t)(i + j) * 1024), "v"(z4));
        }
      }
    }
    if (ww == 7 && lane < 56) {
      char* lp = base + 120 + 7 * 1048576 + 1023 * 1024 + lane * 16;
      asm volatile("global_store_dwordx4 %0, %1, off nt" :: "v"(lp), "v"(z4));
    }
    return;
  }

  // ---------------- COMPUTE ROLE ----------------
  const int l15 = lane & 15;
  const int kg = lane >> 4;
  const int rg = ww >> 2;             // row group (0..1), 64 rows each
  const int cg = ww & 3;              // code group (0..3), 16 codes each

  auto STAGE = [&](int i, int b) {
    const char* g0 = (const char*)ehw + (size_t)i * STEP_BYTES + ww * 4096 + lane * 16;
    char* l0 = s_tiles + b * STEP_BYTES + ww * 4096;  // wave-uniform base
#pragma unroll
    for (int j = 0; j < 4; ++j) {
      __builtin_amdgcn_global_load_lds(
          (const __attribute__((address_space(1))) unsigned int*)(g0 + j * 1024),
          (__attribute__((address_space(3))) unsigned int*)(l0 + j * 1024), 16, 0, 0);
    }
    // c2 table: 256 B; all 8 waves load redundantly (uniform 5 loads/stage)
    const char* g1 = (const char*)ehw + (size_t)i * STEP_BYTES + 32768 + lane * 4;
    char* l1 = s_tiles + b * STEP_BYTES + 32768;
    __builtin_amdgcn_global_load_lds(
        (const __attribute__((address_space(1))) unsigned int*)g1,
        (__attribute__((address_space(3))) unsigned int*)l1, 4, 0, 0);
  };

  const int c_local = cg * 16 + l15;     // lane's code within the 64-code step
  const int rb = c_local * 512;
  const int xm = (l15 & 7) << 4;         // (code&7)<<4

#pragma unroll 1
  for (int p = 0; p < 2; ++p) {
    const int row0 = abid * 256 + p * 128;

    // prologue: stage pipeline 3 deep
    STAGE(0, 0); STAGE(1, 1); STAGE(2, 2);

    // load & convert A fragments: 64 rows/wave (4 subtiles of 16), bf16
    short8 a_h[4][8];
    float x2acc[4];
#pragma unroll
    for (int s = 0; s < 4; ++s) {
      const float* rp = x + (size_t)(row0 + rg * 64 + s * 16 + l15) * D_DIM + kg * 8;
      float s2 = 0.f;
#pragma unroll
      for (int ch = 0; ch < 8; ++ch) {
        const float4* pp = (const float4*)(rp + ch * 32);
        float4 v0 = pp[0], v1 = pp[1];
        float f[8] = {v0.x, v0.y, v0.z, v0.w, v1.x, v1.y, v1.z, v1.w};
#pragma unroll
        for (int j = 0; j < 8; ++j) {
          s2 += f[j] * f[j];
          a_h[s][ch][j] = (short)f2bf_rne(f[j]);
        }
      }
      x2acc[s] = s2;
    }
#pragma unroll
    for (int s = 0; s < 4; ++s) {
      x2acc[s] += __shfl_xor(x2acc[s], 16);
      x2acc[s] += __shfl_xor(x2acc[s], 32);
    }
    if (cg == 0 && lane < 16) {  // kg==0 lanes
#pragma unroll
      for (int s = 0; s < 4; ++s) s_x2[rg * 64 + s * 16 + l15] = x2acc[s];
    }

    float mn[16];
    int mi[16];
#pragma unroll
    for (int s = 0; s < 16; ++s) { mn[s] = 3.4e38f; mi[s] = 0x7fffffff; }

    auto COMPUTE = [&](int t) {
      const char* bh = s_tiles + (t & 3) * STEP_BYTES;
      const int code = t * 64 + c_local;
      const float c2 = *(const float*)(bh + 32768 + c_local * 4);
      short8 vh[8];
#pragma unroll
      for (int ch = 0; ch < 8; ++ch)
        vh[ch] = *(const short8*)(bh + rb + ((ch * 64 + kg * 16) ^ xm));
      f32x4 acc[4];
#pragma unroll
      for (int s = 0; s < 4; ++s) acc[s] = (f32x4){0.f, 0.f, 0.f, 0.f};
#pragma unroll
      for (int ch = 0; ch < 8; ++ch) {
        acc[0] = __builtin_amdgcn_mfma_f32_16x16x32_bf16(a_h[0][ch], vh[ch], acc[0], 0, 0, 0);
        acc[1] = __builtin_amdgcn_mfma_f32_16x16x32_bf16(a_h[1][ch], vh[ch], acc[1], 0, 0, 0);
        acc[2] = __builtin_amdgcn_mfma_f32_16x16x32_bf16(a_h[2][ch], vh[ch], acc[2], 0, 0, 0);
        acc[3] = __builtin_amdgcn_mfma_f32_16x16x32_bf16(a_h[3][ch], vh[ch], acc[3], 0, 0, 0);
      }
#pragma unroll
      for (int s = 0; s < 4; ++s) {
#pragma unroll
        for (int r = 0; r < 4; ++r) {
          float d = __builtin_fmaf(-2.f, acc[s][r], c2);   // |e|^2 - 2 x.e
          if (d < mn[s * 4 + r]) { mn[s * 4 + r] = d; mi[s * 4 + r] = code; }
        }
      }
    };

    // K loop: loads-only vmcnt stream (5 per stage).
    // wait for S_t: younger = S_{t+1}(5) + S_{t+2}(5) = 10.
#pragma unroll 1
    for (int t = 0; t < 125; ++t) {
      asm volatile("s_waitcnt vmcnt(10)" ::: "memory");
      __builtin_amdgcn_s_barrier();
      __builtin_amdgcn_sched_barrier(0);
      COMPUTE(t);
      STAGE(t + 3, (t + 3) & 3);  // overwrites buf (t-1)&3: readers done at barrier
    }
    asm volatile("s_waitcnt vmcnt(10)" ::: "memory");
    __builtin_amdgcn_s_barrier();
    __builtin_amdgcn_sched_barrier(0);
    COMPUTE(125);
    asm volatile("s_waitcnt vmcnt(5)" ::: "memory");
    __builtin_amdgcn_s_barrier();
    __builtin_amdgcn_sched_barrier(0);
    COMPUTE(126);
    asm volatile("s_waitcnt vmcnt(0)" ::: "memory");
    __builtin_amdgcn_s_barrier();
    __builtin_amdgcn_sched_barrier(0);
    COMPUTE(127);

    // reduce across the 16 lanes (l15) holding different codes of same rows
#pragma unroll
    for (int m = 1; m < 16; m <<= 1) {
#pragma unroll
      for (int s = 0; s < 16; ++s) {
        float om = __shfl_xor(mn[s], m);
        int oi = __shfl_xor(mi[s], m);
        if (om < mn[s] || (om == mn[s] && oi < mi[s])) { mn[s] = om; mi[s] = oi; }
      }
    }
    if (l15 == 0) {
#pragma unroll
      for (int s = 0; s < 4; ++s)
#pragma unroll
        for (int r = 0; r < 4; ++r)
          { int lr = rg * 64 + s * 16 + kg * 4 + r;
            s_mn[cg][lr] = mn[s * 4 + r]; s_mi[cg][lr] = mi[s * 4 + r]; }
    }
    __syncthreads();

    // merge 4 code-groups; idx store; histogram; SSE partial
    if (tid < 128) {
      float bm = s_mn[0][tid]; int best = s_mi[0][tid];
#pragma unroll
      for (int c = 1; c < 4; ++c) {
        float m2 = s_mn[c][tid]; int i2 = s_mi[c][tid];
        if (m2 < bm || (m2 == bm && i2 < best)) { bm = m2; best = i2; }
      }
      s_mi[0][tid] = best;                       // publish for gather below
      s_red[tid] = bm + s_x2[tid];               // SSE(row) = dist + |x|^2
      idxb[row0 + tid] = best;                   // scatter_kernel consumes
      atomicAdd(&counts[best], 1);
    }
    __syncthreads();
    for (int m = 64; m > 0; m >>= 1) {
      if (tid < m) s_red[tid] += s_red[tid + m];
      __syncthreads();
    }
    if (tid == 0) ssep[abid * 2 + p] = s_red[0];

    // quantized gather: one wave per 16 rows, coalesced plain scalar stores
    // (dest is 4B-aligned only: quant = out+1).
    for (int r = ww * 16; r < ww * 16 + 16; ++r) {
      int best = s_mi[0][r];
      float4 v = ((const float4*)(cb + (size_t)best * D_DIM))[lane];
      float* qp = quant + (size_t)(row0 + r) * D_DIM + lane * 4;
      qp[0] = v.x; qp[1] = v.y; qp[2] = v.z; qp[3] = v.w;
    }
    // end of pass: protect s_mn/s_mi/s_x2/s_red before next pass re-stages
    __syncthreads();
  }
}

// ---------------------------------------------------------------------------
// One-hot 1.0 scatter — separate dispatch so it orders after ALL argmin
// blocks' zeros (storer blocks are foreign to the row's compute block).
// ---------------------------------------------------------------------------
__global__ __launch_bounds__(256) void scatter_kernel(
    const int* __restrict__ idxb, float* __restrict__ enc) {
  int r = blockIdx.x * 256 + threadIdx.x;
  enc[(size_t)r * K_CODES + idxb[r]] = 1.0f;
}

// ---------------------------------------------------------------------------
// Finalize: vq_loss + perplexity (deterministic fixed-order reductions).
// ---------------------------------------------------------------------------
__global__ __launch_bounds__(256) void finalize_kernel(
    const float* __restrict__ ssep, const int* __restrict__ counts,
    float* __restrict__ out) {
  __shared__ float r1[256], r2[256];
  int t = threadIdx.x;
  float s1 = ssep[t];  // 128 compute blocks x 2 passes, one partial each
  float s2 = 0.f;
  for (int j = 0; j < 32; ++j) {
    float p = (float)counts[t * 32 + j] * (1.0f / 32768.f);
    s2 += p * logf(p + 1e-10f);
  }
  r1[t] = s1; r2[t] = s2;
  __syncthreads();
  for (int m = 128; m > 0; m >>= 1) {
    if (t < m) { r1[t] += r1[t + m]; r2[t] += r2[t + m]; }
    __syncthreads();
  }
  if (t == 0) {
    out[0] = 1.25f * r1[0] / 8388608.f;   // q_latent + 0.25*e_latent
    out[8388609] = expf(-r2[0]);          // perplexity
  }
}

extern "C" void kernel_launch(void* const* d_in, const int* in_sizes, int n_in,
                              void* d_out, int out_size, void* d_ws, size_t ws_size,
                              hipStream_t stream) {
  const float* x = (const float*)d_in[0];
  const float* cb = (const float*)d_in[1];
  float* out = (float*)d_out;
  char* w = (char*)d_ws;
  unsigned short* ehw = (unsigned short*)(w);           // 128 * 33024 B = 4.03 MiB
  int* counts = (int*)(w + 4227072);                    // 32 KiB
  float* ssep = (float*)(w + 4259840);                  // 1 KiB
  int* idxb = (int*)(w + 4260864);                      // 128 KiB

  float* quant = out + 1;
  float* enc = out + 8388610;

  eprep_kernel<<<K_CODES / 4, 256, 0, stream>>>(cb, ehw, counts);
  argmin_kernel<<<256, 512, 0, stream>>>(x, cb, ehw, quant, counts, ssep, idxb, enc);
  scatter_kernel<<<N_ROWS / 256, 256, 0, stream>>>(idxb, enc);
  finalize_kernel<<<1, 256, 0, stream>>>(ssep, counts, out);
}

// Round 7
// 260.541 us; speedup vs baseline: 1.3524x; 1.3524x over previous
//
#include <hip/hip_runtime.h>
#include <stdint.h>

#define N_ROWS 32768
#define K_CODES 8192
#define D_DIM 256
#define STEP_BYTES 33024   // 32 KiB bf16 codes + 256 B fp32 c2 table (16B-aligned)
#define NBUF 4

typedef __attribute__((ext_vector_type(8))) short short8;
typedef __attribute__((ext_vector_type(4))) float f32x4;

__device__ __forceinline__ unsigned short f2bf_rne(float f) {
  union { float f; unsigned u; } v; v.f = f;
  unsigned r = v.u + 0x7fffu + ((v.u >> 16) & 1u);
  return (unsigned short)(r >> 16);
}

// ---------------------------------------------------------------------------
// Prep: codebook fp32 -> bf16 (RNE), XOR-swizzled within each 512B row.
// Each 64-code step tile carries a 256 B fp32 |e|^2 table (exact c2).
// Zeroes counts.
// ---------------------------------------------------------------------------
__global__ __launch_bounds__(256) void eprep_kernel(
    const float* __restrict__ cb, unsigned short* __restrict__ ehw,
    int* __restrict__ counts) {
  int w = threadIdx.x >> 6, lane = threadIdx.x & 63;
  int k = blockIdx.x * 4 + w;
  int gid = blockIdx.x * 256 + threadIdx.x;
  if (gid < K_CODES) counts[gid] = 0;
  const float4* src = (const float4*)(cb + (size_t)k * D_DIM);
  float4 v = src[lane];
  float vv[4] = {v.x, v.y, v.z, v.w};
  unsigned short h[4];
  float s = 0.f;
#pragma unroll
  for (int j = 0; j < 4; ++j) {
    float f = vv[j];
    s += f * f;
    h[j] = f2bf_rne(f);
  }
  char* stepb = (char*)ehw + (size_t)(k >> 6) * STEP_BYTES;
  int cl = k & 63;
  int off = (8 * lane) ^ ((k & 7) << 4);  // swizzle flips bits 4-6 only
  *(ushort4*)(stepb + cl * 512 + off) = make_ushort4(h[0], h[1], h[2], h[3]);
#pragma unroll
  for (int m = 1; m < 64; m <<= 1) s += __shfl_xor(s, m);
  if (lane == 0) *(float*)(stepb + 32768 + cl * 4) = s;  // fp32-exact |e|^2
}

// ---------------------------------------------------------------------------
// Argmin, T3+T4 counted-vmcnt pipeline (depth 3, 4 LDS buffers).
// R7 — revert R6's CU role split (per-CU write cap ~10.5 B/cyc means the
// 1.07 GB zero stream MUST spread over all 256 CUs; 128 dedicated storers
// were the 332 us bottleneck, matching the cap exactly). Back to R5's
// every-block-stores structure with ONE change: VMEM issue moved to the TOP
// of the iteration — [wait][barrier] STAGE(t+3); ZST4(t+3); COMPUTE(t).
// R5 issued stores at the bottom, after ~700 cyc of compute issue, idling
// the write pipe at the top of every iteration. Stream order (L_u W_u per
// iter) is unchanged -> identical vmcnt counts: wait 22, tails 22/13/4,
// 4-iteration store-ack slack. Buffer safety unchanged: STAGE(t+3)
// overwrites buf (t-1)&3 whose readers completed before the barrier.
// 256 blocks x 128 rows; 8 waves = 2 row-groups x 4 code-groups.
// ---------------------------------------------------------------------------
__global__ __launch_bounds__(512, 1) void argmin_kernel(
    const float* __restrict__ x, const float* __restrict__ cb,
    const unsigned short* __restrict__ ehw,
    float* __restrict__ quant, int* __restrict__ counts,
    float* __restrict__ ssep, float* __restrict__ enc) {
  __shared__ __align__(16) char s_tiles[NBUF * STEP_BYTES];  // 129 KiB
  __shared__ float s_x2[128];
  __shared__ float s_red[128];
  // epilogue-only arrays aliased onto s_tiles (buf0 dead after the loop):
  float (*s_mn)[128] = (float (*)[128])(s_tiles);          // 2 KiB
  int (*s_mi)[128] = (int (*)[128])(s_tiles + 2048);       // 2 KiB

  const int tid = threadIdx.x;
  const int abid = blockIdx.x;
  const int ww = tid >> 6;
  const int lane = tid & 63;
  const int l15 = lane & 15;
  const int kg = lane >> 4;
  const int rg = ww >> 2;             // row group (0..1), 64 rows each
  const int cg = ww & 3;              // code group (0..3), 16 codes each
  const int row0 = abid * 128;

  auto STAGE = [&](int i, int b) {
    const char* g0 = (const char*)ehw + (size_t)i * STEP_BYTES + ww * 4096 + lane * 16;
    char* l0 = s_tiles + b * STEP_BYTES + ww * 4096;  // wave-uniform base
#pragma unroll
    for (int j = 0; j < 4; ++j) {
      __builtin_amdgcn_global_load_lds(
          (const __attribute__((address_space(1))) unsigned int*)(g0 + j * 1024),
          (__attribute__((address_space(3))) unsigned int*)(l0 + j * 1024), 16, 0, 0);
    }
    // c2 table: 256 B; ALL 8 waves load it redundantly (same data, same dest)
    // so every wave's vmcnt stream is a uniform 5 loads per stage.
    const char* g1 = (const char*)ehw + (size_t)i * STEP_BYTES + 32768 + lane * 4;
    char* l1 = s_tiles + b * STEP_BYTES + 32768;
    __builtin_amdgcn_global_load_lds(
        (const __attribute__((address_space(1))) unsigned int*)g1,
        (__attribute__((address_space(3))) unsigned int*)l1, 4, 0, 0);
  };

  // Aligned zero-fill bulk: unit u (u=0..127) = 32 KiB at S+120 + u*32768,
  // wave ww covers 4 KiB as 4 x dwordx4 nt (16 B/lane, full 128B lines).
  const f32x4 z4 = {0.f, 0.f, 0.f, 0.f};
  char* Sp = (char*)enc + (size_t)row0 * 32768;           // block region start
  char* zb = Sp + 120 + ww * 4096 + lane * 16;            // aligned bulk base
  auto ZST4 = [&](const char* p) {  // 4 nt stores, 1024 B apart
    asm volatile(
        "global_store_dwordx4 %0, %1, off nt\n\t"
        "global_store_dwordx4 %0, %1, off offset:1024 nt\n\t"
        "global_store_dwordx4 %0, %1, off offset:2048 nt\n\t"
        "global_store_dwordx4 %0, %1, off offset:3072 nt"
        :: "v"(p), "v"(z4));
  };
  // Final-unit variant: unit 127 is 120 B short -> wave 7 lanes>=56 skip the
  // last store (partial-exec instruction still counts once against vmcnt).
  auto ZST4P = [&](const char* p) {
    asm volatile(
        "global_store_dwordx4 %0, %1, off nt\n\t"
        "global_store_dwordx4 %0, %1, off offset:1024 nt\n\t"
        "global_store_dwordx4 %0, %1, off offset:2048 nt"
        :: "v"(p), "v"(z4));
    if (ww < 7 || lane < 56) {
      asm volatile("global_store_dwordx4 %0, %1, off offset:3072 nt"
                   :: "v"(p), "v"(z4));
    }
  };

  // prologue: S0 Z0 S1 Z1 S2 Z2 — younger-than-S0 = 22 from iter 0.
  STAGE(0, 0); ZST4(zb);
  STAGE(1, 1); ZST4(zb + 32768);
  STAGE(2, 2); ZST4(zb + 2 * 32768);

  // load & convert A fragments: 64 rows/wave (4 subtiles of 16), bf16
  short8 a_h[4][8];
  float x2acc[4];
#pragma unroll
  for (int s = 0; s < 4; ++s) {
    const float* rp = x + (size_t)(row0 + rg * 64 + s * 16 + l15) * D_DIM + kg * 8;
    float s2 = 0.f;
#pragma unroll
    for (int ch = 0; ch < 8; ++ch) {
      const float4* p = (const float4*)(rp + ch * 32);
      float4 v0 = p[0], v1 = p[1];
      float f[8] = {v0.x, v0.y, v0.z, v0.w, v1.x, v1.y, v1.z, v1.w};
#pragma unroll
      for (int j = 0; j < 8; ++j) {
        s2 += f[j] * f[j];
        a_h[s][ch][j] = (short)f2bf_rne(f[j]);
      }
    }
    x2acc[s] = s2;
  }
#pragma unroll
  for (int s = 0; s < 4; ++s) {
    x2acc[s] += __shfl_xor(x2acc[s], 16);
    x2acc[s] += __shfl_xor(x2acc[s], 32);
  }
  if (cg == 0 && lane < 16) {  // kg==0 lanes
#pragma unroll
    for (int s = 0; s < 4; ++s) s_x2[rg * 64 + s * 16 + l15] = x2acc[s];
  }

  float mn[16];
  int mi[16];
#pragma unroll
  for (int s = 0; s < 16; ++s) { mn[s] = 3.4e38f; mi[s] = 0x7fffffff; }

  const int c_local = cg * 16 + l15;     // lane's code within the 64-code step
  const int rb = c_local * 512;
  const int xm = (l15 & 7) << 4;         // (code&7)<<4

  // COMPUTE (pure): preload 8 vh (ds_read_b128) + scalar c2 (ds_read_b32
  // broadcast), 32 MFMA, min-update.
  auto COMPUTE = [&](int t) {
    const char* bh = s_tiles + (t & 3) * STEP_BYTES;
    const int code = t * 64 + c_local;
    const float c2 = *(const float*)(bh + 32768 + c_local * 4);
    short8 vh[8];
#pragma unroll
    for (int ch = 0; ch < 8; ++ch)
      vh[ch] = *(const short8*)(bh + rb + ((ch * 64 + kg * 16) ^ xm));
    f32x4 acc[4];
#pragma unroll
    for (int s = 0; s < 4; ++s) acc[s] = (f32x4){0.f, 0.f, 0.f, 0.f};
#pragma unroll
    for (int ch = 0; ch < 8; ++ch) {
      acc[0] = __builtin_amdgcn_mfma_f32_16x16x32_bf16(a_h[0][ch], vh[ch], acc[0], 0, 0, 0);
      acc[1] = __builtin_amdgcn_mfma_f32_16x16x32_bf16(a_h[1][ch], vh[ch], acc[1], 0, 0, 0);
      acc[2] = __builtin_amdgcn_mfma_f32_16x16x32_bf16(a_h[2][ch], vh[ch], acc[2], 0, 0, 0);
      acc[3] = __builtin_amdgcn_mfma_f32_16x16x32_bf16(a_h[3][ch], vh[ch], acc[3], 0, 0, 0);
    }
#pragma unroll
    for (int s = 0; s < 4; ++s) {
#pragma unroll
      for (int r = 0; r < 4; ++r) {
        float d = __builtin_fmaf(-2.f, acc[s][r], c2);   // |e|^2 - 2 x.e
        if (d < mn[s * 4 + r]) { mn[s * 4 + r] = d; mi[s * 4 + r] = code; }
      }
    }
  };

  // iter t: stage tile t+3 + zero unit t+3 FIRST (VMEM issues ~100 cyc after
  // the barrier, drains under COMPUTE), then COMPUTE tile t.
  // wait for S_t: younger = Z_t(4)+S_{t+1}(5)+Z_{t+1}(4)+S_{t+2}(5)+Z_{t+2}(4)
  // = 22; stores issued in iter u must ack by top of iter u+4.
#pragma unroll 1
  for (int t = 0; t < 124; ++t) {
    asm volatile("s_waitcnt vmcnt(22)" ::: "memory");
    __builtin_amdgcn_s_barrier();
    __builtin_amdgcn_sched_barrier(0);
    STAGE(t + 3, (t + 3) & 3);  // overwrites buf (t-1)&3: readers done at barrier
    ZST4(zb + (size_t)(t + 3) * 32768);
    COMPUTE(t);
  }
  // t=124: stages tile 127, zeroes final unit 127 (predicated last store).
  asm volatile("s_waitcnt vmcnt(22)" ::: "memory");
  __builtin_amdgcn_s_barrier();
  __builtin_amdgcn_sched_barrier(0);
  STAGE(127, 127 & 3);
  ZST4P(zb + (size_t)127 * 32768);
  COMPUTE(124);
  // t=125: younger than S_125 = Z125u(4)+S126(5)+Z126u(4)+S127(5)+Z127u(4)=22.
  asm volatile("s_waitcnt vmcnt(22)" ::: "memory");
  __builtin_amdgcn_s_barrier();
  __builtin_amdgcn_sched_barrier(0);
  COMPUTE(125);
  // t=126: younger than S_126 = Z126u(4)+S127(5)+Z127u(4) = 13.
  asm volatile("s_waitcnt vmcnt(13)" ::: "memory");
  __builtin_amdgcn_s_barrier();
  __builtin_amdgcn_sched_barrier(0);
  COMPUTE(126);
  // t=127: younger than S_127 = Z127u(4).
  asm volatile("s_waitcnt vmcnt(4)" ::: "memory");
  __builtin_amdgcn_s_barrier();
  __builtin_amdgcn_sched_barrier(0);
  COMPUTE(127);

  // head 120 B + tail 8 B of the block's enc region (mod-128 remainders)
  if (tid < 30) ((float*)Sp)[tid] = 0.f;
  if (tid < 2) *(float*)(Sp + 4194296 + 4 * tid) = 0.f;

  // reduce across the 16 lanes (l15) holding different codes of the same rows
#pragma unroll
  for (int m = 1; m < 16; m <<= 1) {
#pragma unroll
    for (int s = 0; s < 16; ++s) {
      float om = __shfl_xor(mn[s], m);
      int oi = __shfl_xor(mi[s], m);
      if (om < mn[s] || (om == mn[s] && oi < mi[s])) { mn[s] = om; mi[s] = oi; }
    }
  }
  if (l15 == 0) {
#pragma unroll
    for (int s = 0; s < 4; ++s)
#pragma unroll
      for (int r = 0; r < 4; ++r)
        { int lr = rg * 64 + s * 16 + kg * 4 + r;
          s_mn[cg][lr] = mn[s * 4 + r]; s_mi[cg][lr] = mi[s * 4 + r]; }
  }
  // drain this wave's zero stores; barrier => all waves' zeros ordered at L2
  // before any 1.0 one-hot store below.
  asm volatile("s_waitcnt vmcnt(0)" ::: "memory");
  __syncthreads();

  // merge 4 code-groups; one-hot 1.0 scatter; histogram; SSE partial
  if (tid < 128) {
    float bm = s_mn[0][tid]; int best = s_mi[0][tid];
#pragma unroll
    for (int c = 1; c < 4; ++c) {
      float m2 = s_mn[c][tid]; int i2 = s_mi[c][tid];
      if (m2 < bm || (m2 == bm && i2 < best)) { bm = m2; best = i2; }
    }
    s_mi[0][tid] = best;                       // publish for gather below
    s_red[tid] = bm + s_x2[tid];               // SSE(row) = dist + |x|^2
    enc[(size_t)(row0 + tid) * K_CODES + best] = 1.0f;
    atomicAdd(&counts[best], 1);
  }
  __syncthreads();
  for (int m = 64; m > 0; m >>= 1) {
    if (tid < m) s_red[tid] += s_red[tid + m];
    __syncthreads();
  }
  if (tid == 0) ssep[abid] = s_red[0];

  // quantized gather: one wave per 16 rows, coalesced plain scalar stores
  // (dest is 4B-aligned only: quant = out+1).
  for (int r = ww * 16; r < ww * 16 + 16; ++r) {
    int best = s_mi[0][r];
    float4 v = ((const float4*)(cb + (size_t)best * D_DIM))[lane];
    float* qp = quant + (size_t)(row0 + r) * D_DIM + lane * 4;
    qp[0] = v.x; qp[1] = v.y; qp[2] = v.z; qp[3] = v.w;
  }
}

// ---------------------------------------------------------------------------
// Finalize: vq_loss + perplexity (deterministic fixed-order reductions).
// ---------------------------------------------------------------------------
__global__ __launch_bounds__(256) void finalize_kernel(
    const float* __restrict__ ssep, const int* __restrict__ counts,
    float* __restrict__ out) {
  __shared__ float r1[256], r2[256];
  int t = threadIdx.x;
  float s1 = ssep[t];  // 256 argmin blocks, one partial each
  float s2 = 0.f;
  for (int j = 0; j < 32; ++j) {
    float p = (float)counts[t * 32 + j] * (1.0f / 32768.f);
    s2 += p * logf(p + 1e-10f);
  }
  r1[t] = s1; r2[t] = s2;
  __syncthreads();
  for (int m = 128; m > 0; m >>= 1) {
    if (t < m) { r1[t] += r1[t + m]; r2[t] += r2[t + m]; }
    __syncthreads();
  }
  if (t == 0) {
    out[0] = 1.25f * r1[0] / 8388608.f;   // q_latent + 0.25*e_latent
    out[8388609] = expf(-r2[0]);          // perplexity
  }
}

extern "C" void kernel_launch(void* const* d_in, const int* in_sizes, int n_in,
                              void* d_out, int out_size, void* d_ws, size_t ws_size,
                              hipStream_t stream) {
  const float* x = (const float*)d_in[0];
  const float* cb = (const float*)d_in[1];
  float* out = (float*)d_out;
  char* w = (char*)d_ws;
  unsigned short* ehw = (unsigned short*)(w);           // 128 * 33024 B = 4.03 MiB
  int* counts = (int*)(w + 4227072);                    // 32 KiB
  float* ssep = (float*)(w + 4259840);                  // 1 KiB

  float* quant = out + 1;
  float* enc = out + 8388610;

  eprep_kernel<<<K_CODES / 4, 256, 0, stream>>>(cb, ehw, counts);
  argmin_kernel<<<256, 512, 0, stream>>>(x, cb, ehw, quant, counts, ssep, enc);
  finalize_kernel<<<1, 256, 0, stream>>>(ssep, counts, out);
}

// Round 9
// 241.439 us; speedup vs baseline: 1.4594x; 1.0791x over previous
//
#include <hip/hip_runtime.h>
#include <stdint.h>

#define N_ROWS 32768
#define K_CODES 8192
#define D_DIM 256
#define STEP_BYTES 33024   // 32 KiB bf16 codes + 256 B fp32 c2 table (16B-aligned)
#define NBUF 4

typedef __attribute__((ext_vector_type(8))) short short8;
typedef __attribute__((ext_vector_type(4))) float f32x4;

__device__ __forceinline__ unsigned short f2bf_rne(float f) {
  union { float f; unsigned u; } v; v.f = f;
  unsigned r = v.u + 0x7fffu + ((v.u >> 16) & 1u);
  return (unsigned short)(r >> 16);
}

// ---------------------------------------------------------------------------
// Prep: codebook fp32 -> bf16 (RNE), XOR-swizzled within each 512B row.
// Each 64-code step tile carries a 256 B fp32 |e|^2 table. Zeroes counts.
// (unchanged from R5)
// ---------------------------------------------------------------------------
__global__ __launch_bounds__(256) void eprep_kernel(
    const float* __restrict__ cb, unsigned short* __restrict__ ehw,
    int* __restrict__ counts) {
  int w = threadIdx.x >> 6, lane = threadIdx.x & 63;
  int k = blockIdx.x * 4 + w;
  int gid = blockIdx.x * 256 + threadIdx.x;
  if (gid < K_CODES) counts[gid] = 0;
  const float4* src = (const float4*)(cb + (size_t)k * D_DIM);
  float4 v = src[lane];
  float vv[4] = {v.x, v.y, v.z, v.w};
  unsigned short h[4];
  float s = 0.f;
#pragma unroll
  for (int j = 0; j < 4; ++j) {
    float f = vv[j];
    s += f * f;
    h[j] = f2bf_rne(f);
  }
  char* stepb = (char*)ehw + (size_t)(k >> 6) * STEP_BYTES;
  int cl = k & 63;
  int off = (8 * lane) ^ ((k & 7) << 4);  // swizzle flips bits 4-6 only
  *(ushort4*)(stepb + cl * 512 + off) = make_ushort4(h[0], h[1], h[2], h[3]);
#pragma unroll
  for (int m = 1; m < 64; m <<= 1) s += __shfl_xor(s, m);
  if (lane == 0) *(float*)(stepb + 32768 + cl * 4) = s;  // fp32-exact |e|^2
}

// ---------------------------------------------------------------------------
// Argmin R8b — per-CU read-traffic halving via (row-group x codebook-half)
// decomposition. Evidence: R5 sits at a per-CU combined-VMEM cap ~16 B/cyc
// (measured 15.4 sustained; R6 isolated the 10.5 write-only cap). R5's CU
// read bill was 4.03 MiB codebook per 128 rows. Now: 256 blocks = 128
// row-groups (256 rows) x 2 codebook halves (4096 codes = 64 tiles): per-CU
// reads 2.02 MiB + x 0.25 -> combined 6.6 MiB (was 8.29).
//   - 8 waves x 32 rows each (2 row-subtiles); per tile, 4 sequential
//     16-code subtiles reuse vh/acc regs (VGPR ~170). No cross-wave merge:
//     each wave owns its rows; 16-lane reduce only.
//   - zero-fill: block abid zeros enc rows abid*128..+127 (4 MiB), 64 KiB
//     per iter (8 dwordx4 nt per wave), aligned full lines (R4), nt (R3).
//     (global_store imm offset is 13-bit SIGNED -> two base regs, imms<=3072)
//   - vmcnt stream: 5 loads + 8 stores per iter; wait 34 uniform
//     (= Z_t(8)+S(5)+Z(8)+S(5)+Z(8)); tails 34/21/8; store slack 4 iters.
//   - per-half (dist,idx) + |x|^2 go to workspace; merge_kernel finishes.
// ---------------------------------------------------------------------------
__global__ __launch_bounds__(512, 1) void argmin_kernel(
    const float* __restrict__ x, const unsigned short* __restrict__ ehw,
    float* __restrict__ dmh, int* __restrict__ mih,
    float* __restrict__ x2g, float* __restrict__ enc) {
  __shared__ __align__(16) char s_tiles[NBUF * STEP_BYTES];  // 129 KiB

  const int tid = threadIdx.x;
  const int abid = blockIdx.x;
  const int r = abid >> 1;            // row-group (0..127): rows r*256..+255
  const int h = abid & 1;             // codebook half: codes h*4096..+4095
  const int ww = tid >> 6;
  const int lane = tid & 63;
  const int l15 = lane & 15;
  const int kg = lane >> 4;
  const int row0c = r * 256;          // compute rows base
  const int row0z = abid * 128;       // zero-fill region rows base (own 4MiB)

  auto STAGE = [&](int i, int b) {    // i = tile index within half (0..63)
    const char* g0 = (const char*)ehw + (size_t)(h * 64 + i) * STEP_BYTES
                     + ww * 4096 + lane * 16;
    char* l0 = s_tiles + b * STEP_BYTES + ww * 4096;  // wave-uniform base
#pragma unroll
    for (int j = 0; j < 4; ++j) {
      __builtin_amdgcn_global_load_lds(
          (const __attribute__((address_space(1))) unsigned int*)(g0 + j * 1024),
          (__attribute__((address_space(3))) unsigned int*)(l0 + j * 1024), 16, 0, 0);
    }
    // c2 table: 256 B; all 8 waves load redundantly (uniform 5 loads/stage)
    const char* g1 = (const char*)ehw + (size_t)(h * 64 + i) * STEP_BYTES
                     + 32768 + lane * 4;
    char* l1 = s_tiles + b * STEP_BYTES + 32768;
    __builtin_amdgcn_global_load_lds(
        (const __attribute__((address_space(1))) unsigned int*)g1,
        (__attribute__((address_space(3))) unsigned int*)l1, 4, 0, 0);
  };

  // zero-fill: 64 units of 64 KiB (unit 63 short by 128 B). Wave ww covers
  // 8 KiB/unit as 8 x dwordx4 nt (full 128B lines; region starts at byte 8
  // mod 128 -> head 120 B + tail 8 B via epilogue scalars). Two base regs
  // because the store's imm offset is 13-bit signed (<=4095).
  const f32x4 z4 = {0.f, 0.f, 0.f, 0.f};
  char* Sp = (char*)enc + (size_t)row0z * 32768;     // block region start
  char* zb = Sp + 120 + ww * 8192 + lane * 16;       // aligned bulk base
  auto ZST8 = [&](const char* p) {
    const char* q = p + 4096;
    asm volatile(
        "global_store_dwordx4 %0, %2, off nt\n\t"
        "global_store_dwordx4 %0, %2, off offset:1024 nt\n\t"
        "global_store_dwordx4 %0, %2, off offset:2048 nt\n\t"
        "global_store_dwordx4 %0, %2, off offset:3072 nt\n\t"
        "global_store_dwordx4 %1, %2, off nt\n\t"
        "global_store_dwordx4 %1, %2, off offset:1024 nt\n\t"
        "global_store_dwordx4 %1, %2, off offset:2048 nt\n\t"
        "global_store_dwordx4 %1, %2, off offset:3072 nt"
        :: "v"(p), "v"(q), "v"(z4));
  };
  auto ZST8P = [&](const char* p) {   // unit 63: wave 7 lanes>=56 skip last
    const char* q = p + 4096;
    asm volatile(
        "global_store_dwordx4 %0, %2, off nt\n\t"
        "global_store_dwordx4 %0, %2, off offset:1024 nt\n\t"
        "global_store_dwordx4 %0, %2, off offset:2048 nt\n\t"
        "global_store_dwordx4 %0, %2, off offset:3072 nt\n\t"
        "global_store_dwordx4 %1, %2, off nt\n\t"
        "global_store_dwordx4 %1, %2, off offset:1024 nt\n\t"
        "global_store_dwordx4 %1, %2, off offset:2048 nt"
        :: "v"(p), "v"(q), "v"(z4));
    if (ww < 7 || lane < 56) {
      asm volatile("global_store_dwordx4 %0, %1, off offset:3072 nt"
                   :: "v"(q), "v"(z4));
    }
  };

  // prologue: S0 Z0 S1 Z1 S2 Z2 — younger-than-S0 = 34 from iter 0.
  STAGE(0, 0); ZST8(zb);
  STAGE(1, 1); ZST8(zb + 65536);
  STAGE(2, 2); ZST8(zb + 2 * 65536);

  // A fragments: 32 rows/wave (2 subtiles of 16), bf16; |x|^2 to workspace.
  short8 a_h[2][8];
  float x2acc[2];
#pragma unroll
  for (int s = 0; s < 2; ++s) {
    const float* rp = x + (size_t)(row0c + ww * 32 + s * 16 + l15) * D_DIM + kg * 8;
    float s2 = 0.f;
#pragma unroll
    for (int ch = 0; ch < 8; ++ch) {
      const float4* p = (const float4*)(rp + ch * 32);
      float4 v0 = p[0], v1 = p[1];
      float f[8] = {v0.x, v0.y, v0.z, v0.w, v1.x, v1.y, v1.z, v1.w};
#pragma unroll
      for (int j = 0; j < 8; ++j) {
        s2 += f[j] * f[j];
        a_h[s][ch][j] = (short)f2bf_rne(f[j]);
      }
    }
    x2acc[s] = s2;
  }
#pragma unroll
  for (int s = 0; s < 2; ++s) {
    x2acc[s] += __shfl_xor(x2acc[s], 16);
    x2acc[s] += __shfl_xor(x2acc[s], 32);
  }
  if (lane < 16) {  // kg==0 lanes; both halves write identical values: benign
#pragma unroll
    for (int s = 0; s < 2; ++s)
      x2g[row0c + ww * 32 + s * 16 + l15] = x2acc[s];
  }

  float mn[8];
  int mi[8];
#pragma unroll
  for (int s = 0; s < 8; ++s) { mn[s] = 3.4e38f; mi[s] = 0x7fffffff; }

  const int xm = (l15 & 7) << 4;      // swizzle term: (code&7)<<4

  // COMPUTE: 4 sequential 16-code subtiles; vh/acc regs reused across cs.
  auto COMPUTE = [&](int t) {
    const char* bh = s_tiles + (t & 3) * STEP_BYTES;
#pragma unroll
    for (int cs = 0; cs < 4; ++cs) {
      const int c_l = cs * 16 + l15;          // code within the 64-code tile
      const int code = h * 4096 + t * 64 + c_l;
      const float c2 = *(const float*)(bh + 32768 + c_l * 4);
      const int rb = c_l * 512;
      short8 vh[8];
#pragma unroll
      for (int ch = 0; ch < 8; ++ch)
        vh[ch] = *(const short8*)(bh + rb + ((ch * 64 + kg * 16) ^ xm));
      f32x4 acc[2];
      acc[0] = (f32x4){0.f, 0.f, 0.f, 0.f};
      acc[1] = (f32x4){0.f, 0.f, 0.f, 0.f};
#pragma unroll
      for (int ch = 0; ch < 8; ++ch) {
        acc[0] = __builtin_amdgcn_mfma_f32_16x16x32_bf16(a_h[0][ch], vh[ch], acc[0], 0, 0, 0);
        acc[1] = __builtin_amdgcn_mfma_f32_16x16x32_bf16(a_h[1][ch], vh[ch], acc[1], 0, 0, 0);
      }
#pragma unroll
      for (int s = 0; s < 2; ++s) {
#pragma unroll
        for (int q = 0; q < 4; ++q) {
          float d = __builtin_fmaf(-2.f, acc[s][q], c2);   // |e|^2 - 2 x.e
          if (d < mn[s * 4 + q]) { mn[s * 4 + q] = d; mi[s * 4 + q] = code; }
        }
      }
    }
  };

  // K loop over 64 tiles. iter t: COMPUTE(t); STAGE(t+3); ZST8(unit t+3).
  // wait for S_t: younger = Z_t(8)+S_{t+1}(5)+Z_{t+1}(8)+S_{t+2}(5)+Z_{t+2}(8)
  // = 34; stores issued in iter u ack by top of iter u+4.
#pragma unroll 1
  for (int t = 0; t < 60; ++t) {
    asm volatile("s_waitcnt vmcnt(34)" ::: "memory");
    __builtin_amdgcn_s_barrier();
    __builtin_amdgcn_sched_barrier(0);
    COMPUTE(t);
    STAGE(t + 3, (t + 3) & 3);  // overwrites buf (t-1)&3: readers done at barrier
    ZST8(zb + (size_t)(t + 3) * 65536);
  }
  // t=60: stages tile 63, zeroes final (short) unit 63.
  asm volatile("s_waitcnt vmcnt(34)" ::: "memory");
  __builtin_amdgcn_s_barrier();
  __builtin_amdgcn_sched_barrier(0);
  COMPUTE(60);
  STAGE(63, 63 & 3);
  ZST8P(zb + (size_t)63 * 65536);
  // t=61: younger-than-S_61 = Z61(8)+S62(5)+Z62(8)+S63(5)+Z63(8) = 34.
  asm volatile("s_waitcnt vmcnt(34)" ::: "memory");
  __builtin_amdgcn_s_barrier();
  __builtin_amdgcn_sched_barrier(0);
  COMPUTE(61);
  // t=62: younger-than-S_62 = Z62(8)+S63(5)+Z63(8) = 21.
  asm volatile("s_waitcnt vmcnt(21)" ::: "memory");
  __builtin_amdgcn_s_barrier();
  __builtin_amdgcn_sched_barrier(0);
  COMPUTE(62);
  // t=63: younger-than-S_63 = Z63(8).
  asm volatile("s_waitcnt vmcnt(8)" ::: "memory");
  __builtin_amdgcn_s_barrier();
  __builtin_amdgcn_sched_barrier(0);
  COMPUTE(63);

  // head 120 B + tail 8 B of the block's enc region (mod-128 remainders)
  if (tid < 30) ((float*)Sp)[tid] = 0.f;
  if (tid < 2) *(float*)(Sp + 4194296 + 4 * tid) = 0.f;

  // reduce across the 16 lanes (l15) holding different codes of the same rows
#pragma unroll
  for (int m = 1; m < 16; m <<= 1) {
#pragma unroll
    for (int s = 0; s < 8; ++s) {
      float om = __shfl_xor(mn[s], m);
      int oi = __shfl_xor(mi[s], m);
      if (om < mn[s] || (om == mn[s] && oi < mi[s])) { mn[s] = om; mi[s] = oi; }
    }
  }
  // per-half result: row = row0c + ww*32 + s*16 + kg*4 + q  (l15==0 lanes)
  if (l15 == 0) {
    float* dmo = dmh + (size_t)h * N_ROWS;
    int* mio = mih + (size_t)h * N_ROWS;
#pragma unroll
    for (int s = 0; s < 2; ++s)
#pragma unroll
      for (int q = 0; q < 4; ++q) {
        int row = row0c + ww * 32 + s * 16 + kg * 4 + q;
        dmo[row] = mn[s * 4 + q];
        mio[row] = mi[s * 4 + q];
      }
  }
}

// ---------------------------------------------------------------------------
// Merge halves + epilogue: pick best of the two codebook halves per row
// (tie -> half 0, whose indices are smaller = reference argmin tiebreak),
// one-hot 1.0, histogram, SSE partials, quantized gather. Separate dispatch
// orders it after ALL argmin blocks' zero stores.
// ---------------------------------------------------------------------------
__global__ __launch_bounds__(256) void merge_kernel(
    const float* __restrict__ dmh, const int* __restrict__ mih,
    const float* __restrict__ x2g, const float* __restrict__ cb,
    float* __restrict__ quant, float* __restrict__ enc,
    int* __restrict__ counts, float* __restrict__ ssep) {
  __shared__ int s_bi[128];
  __shared__ float s_red[128];
  const int p = blockIdx.x;
  const int tid = threadIdx.x;
  if (tid < 128) {
    int row = p * 128 + tid;
    float d0 = dmh[row], d1 = dmh[N_ROWS + row];
    int i0 = mih[row], i1 = mih[N_ROWS + row];
    int best = (d1 < d0) ? i1 : i0;         // tie -> i0 (smaller index)
    float bm = (d1 < d0) ? d1 : d0;
    s_bi[tid] = best;
    s_red[tid] = bm + x2g[row];             // SSE(row) = dist + |x|^2
    enc[(size_t)row * K_CODES + best] = 1.0f;
    atomicAdd(&counts[best], 1);
  }
  __syncthreads();
  for (int m = 64; m > 0; m >>= 1) {
    if (tid < m) s_red[tid] += s_red[tid + m];
    __syncthreads();
  }
  if (tid == 0) ssep[p] = s_red[0];

  // quantized gather: 4 waves x 32 rows, coalesced scalar stores
  // (dest is 4B-aligned only: quant = out+1).
  const int ww = tid >> 6, lane = tid & 63;
  for (int rr = ww * 32; rr < ww * 32 + 32; ++rr) {
    int best = s_bi[rr];
    float4 v = ((const float4*)(cb + (size_t)best * D_DIM))[lane];
    float* qp = quant + (size_t)(p * 128 + rr) * D_DIM + lane * 4;
    qp[0] = v.x; qp[1] = v.y; qp[2] = v.z; qp[3] = v.w;
  }
}

// ---------------------------------------------------------------------------
// Finalize: vq_loss + perplexity (deterministic fixed-order reductions).
// ---------------------------------------------------------------------------
__global__ __launch_bounds__(256) void finalize_kernel(
    const float* __restrict__ ssep, const int* __restrict__ counts,
    float* __restrict__ out) {
  __shared__ float r1[256], r2[256];
  int t = threadIdx.x;
  float s1 = ssep[t];  // 256 merge blocks, one partial each
  float s2 = 0.f;
  for (int j = 0; j < 32; ++j) {
    float p = (float)counts[t * 32 + j] * (1.0f / 32768.f);
    s2 += p * logf(p + 1e-10f);
  }
  r1[t] = s1; r2[t] = s2;
  __syncthreads();
  for (int m = 128; m > 0; m >>= 1) {
    if (t < m) { r1[t] += r1[t + m]; r2[t] += r2[t + m]; }
    __syncthreads();
  }
  if (t == 0) {
    out[0] = 1.25f * r1[0] / 8388608.f;   // q_latent + 0.25*e_latent
    out[8388609] = expf(-r2[0]);          // perplexity
  }
}

extern "C" void kernel_launch(void* const* d_in, const int* in_sizes, int n_in,
                              void* d_out, int out_size, void* d_ws, size_t ws_size,
                              hipStream_t stream) {
  const float* x = (const float*)d_in[0];
  const float* cb = (const float*)d_in[1];
  float* out = (float*)d_out;
  char* w = (char*)d_ws;
  unsigned short* ehw = (unsigned short*)(w);           // 128*33024 = 4,227,072 B
  int* counts = (int*)(w + 4227072);                    // 32 KiB
  float* ssep = (float*)(w + 4259840);                  // 1 KiB (256 used)
  float* dmh = (float*)(w + 4260864);                   // [2][32768] f32 = 256 KiB
  int* mih = (int*)(w + 4523008);                       // [2][32768] i32 = 256 KiB
  float* x2g = (float*)(w + 4785152);                   // [32768] f32 = 128 KiB

  float* quant = out + 1;
  float* enc = out + 8388610;

  eprep_kernel<<<K_CODES / 4, 256, 0, stream>>>(cb, ehw, counts);
  argmin_kernel<<<256, 512, 0, stream>>>(x, ehw, dmh, mih, x2g, enc);
  merge_kernel<<<256, 256, 0, stream>>>(dmh, mih, x2g, cb, quant, enc, counts, ssep);
  finalize_kernel<<<1, 256, 0, stream>>>(ssep, counts, out);
}